// Round 10
// baseline (71.708 us; speedup 1.0000x reference)
//
#include <hip/hip_runtime.h>

typedef unsigned short u16;
typedef unsigned int   u32;
typedef short s8v  __attribute__((ext_vector_type(8)));   // 8 bf16 (4 VGPR)
typedef float f16v __attribute__((ext_vector_type(16)));  // 32x32 acc
typedef unsigned int u32x4 __attribute__((ext_vector_type(4)));

#define ROWBYTES 4224                 // 4 c-chunks * (66 px * 16 B)
#define NROWS    18                   // 16 output rows + 2 halo
#define TILEB    (NROWS * ROWBYTES)   // 76032 B per buffer
#define NT       4                    // tiles per persistent block

__device__ inline u16 f2bf(float f) {
    u32 u = __builtin_bit_cast(u32, f);
    u += 0x7FFFu + ((u >> 16) & 1u);   // RNE; inputs finite
    return (u16)(u >> 16);
}
__device__ inline u32 pk2(float lo, float hi) {
    return (u32)f2bf(lo) | ((u32)f2bf(hi) << 16);
}

// Persistent-block pipelined fused conv: 256 blocks (1/CU), 512 thr = 8 waves,
// double-buffered 2x76KB LDS. Per tile: issue next tile's global loads into
// registers FIRST, compute current tile (MFMA) while they fly, then convert +
// ds_write next buffer, one barrier. Loads are in flight ~continuously.
// Block owns 4 vertically-adjacent 32o x 64w x 16h tiles.
__global__ __launch_bounds__(512, 2) void k_fused(const float* __restrict__ x,
                                                  const float* __restrict__ wgt,
                                                  const float* __restrict__ bias,
                                                  const float* __restrict__ scale_p,
                                                  float* __restrict__ out) {
    __shared__ __align__(16) char lds[2 * TILEB];   // 152064 B

    // XCD swizzle (grid 256): 32 dispatch-consecutive blocks (= 2 full images:
    // all wb/hsq siblings) land on one XCD -> shared input rows in its L2.
    const int bid     = blockIdx.x;
    const int logical = ((bid & 7) << 5) | (bid >> 3);
    const int n   = logical >> 4;
    const int hsq = (logical >> 2) & 3;              // vertical quarter
    const int wb  = logical & 3;
    const int w0  = wb << 6;
    const int t    = threadIdx.x;
    const int l    = t & 63;
    const int wave = t >> 6;                         // 0..7
    const int g    = l >> 5;
    const int ln   = l & 31;
    const int chunk = wave & 3;                      // c-chunk
    const int half  = wave >> 2;                     // row parity

    // ---- weight repack into LDS overlay: [o][c][9] f32 -> [tap][o*32+c] bf16
    {
        u16* wl = (u16*)lds;
        #pragma unroll
        for (int k = 0; k < 18; ++k) {               // 9216 = 18*512
            const int idx = t + (k << 9);
            const int tap = idx % 9;
            const int oc  = idx / 9;
            wl[tap * 1024 + oc] = f2bf(wgt[idx]);
        }
    }
    __syncthreads();

    s8v A[9][2];
    {
        const u16* wl = (const u16*)lds;
        #pragma unroll
        for (int tap = 0; tap < 9; ++tap)
            #pragma unroll
            for (int q = 0; q < 2; ++q)
                A[tap][q] = *(const s8v*)(wl + tap * 1024 + ln * 32 + q * 16 + g * 8);
    }
    const float scale = scale_p[0];
    float bias_r[16];
    #pragma unroll
    for (int rg = 0; rg < 16; ++rg) bias_r[rg] = bias[(rg & 3) + 8 * (rg >> 2) + 4 * g];
    __syncthreads();   // overlay free

    const float* xbase = x + ((size_t)n << 21);      // n*32*65536
    const float* pb    = xbase + (size_t)(chunk * 8) * 65536 + w0 + l;

    float v[9][8];     // main staged loads (this wave: 9 rows x 8 channels)
    float hv[8];       // halo staged loads (threads t<144)

    // Phase A: issue all of tile hs's loads into registers (clamped, branch-free)
    auto issueA = [&](int hs) {
        const int h0 = hs << 4;
        #pragma unroll
        for (int j = 0; j < 9; ++j) {
            const int hin = h0 - 1 + half + (j << 1);
            const int hcl = hin < 0 ? 0 : (hin > 255 ? 255 : hin);
            const float* p = pb + (size_t)hcl * 256;
            #pragma unroll
            for (int c = 0; c < 8; ++c) v[j][c] = p[(size_t)c * 65536];
        }
        if (t < 144) {                               // halo px ps=0 / ps=65
            const int cc = t / 36, rem = t - cc * 36, side = rem / 18, r = rem - side * 18;
            const int hin = h0 - 1 + r;
            const int hcl = hin < 0 ? 0 : (hin > 255 ? 255 : hin);
            const int wg  = w0 - 1 + side * 65;
            const int wcl = wg < 0 ? 0 : (wg > 255 ? 255 : wg);
            const float* p = xbase + (size_t)(cc * 8) * 65536 + (size_t)hcl * 256 + wcl;
            #pragma unroll
            for (int c = 0; c < 8; ++c) hv[c] = p[(size_t)c * 65536];
        }
    };

    // Phase C: zero-select OOB, convert, contiguous b128 LDS writes
    auto writeC = [&](int hs, char* buf) {
        const int h0 = hs << 4;
        #pragma unroll
        for (int j = 0; j < 9; ++j) {
            const int hin = h0 - 1 + half + (j << 1);
            const bool bad = (hin < 0) || (hin > 255);
            #pragma unroll
            for (int c = 0; c < 8; ++c) v[j][c] = bad ? 0.f : v[j][c];
        }
        char* ldst = buf + chunk * 1056 + ((l + 1) << 4);
        #pragma unroll
        for (int j = 0; j < 9; ++j) {
            const int r = half + (j << 1);
            *(u32x4*)(ldst + r * ROWBYTES) = u32x4{
                pk2(v[j][0], v[j][1]), pk2(v[j][2], v[j][3]),
                pk2(v[j][4], v[j][5]), pk2(v[j][6], v[j][7])};
        }
        if (t < 144) {
            const int cc = t / 36, rem = t - cc * 36, side = rem / 18, r = rem - side * 18;
            const int hin = h0 - 1 + r;
            const int wg  = w0 - 1 + side * 65;
            const bool bad = (hin < 0) || (hin > 255) || (wg < 0) || (wg > 255);
            #pragma unroll
            for (int c = 0; c < 8; ++c) hv[c] = bad ? 0.f : hv[c];
            *(u32x4*)(buf + r * ROWBYTES + cc * 1056 + side * 1040) = u32x4{
                pk2(hv[0], hv[1]), pk2(hv[2], hv[3]),
                pk2(hv[4], hv[5]), pk2(hv[6], hv[7])};
        }
    };

    // Phase B: compute one tile from buf; each wave does 2 output rows
    auto compute = [&](int hs, const char* buf) {
        const int h0 = hs << 4;
        #pragma unroll
        for (int i = 0; i < 2; ++i) {
            const int hr = (wave << 1) + i;          // 0..15

            f16v acc0, acc1;
            #pragma unroll
            for (int rg = 0; rg < 16; ++rg) { acc0[rg] = 0.f; acc1[rg] = 0.f; }

            #pragma unroll
            for (int kh = 0; kh < 3; ++kh) {
                const char* rowp = buf + (hr + kh) * ROWBYTES + g * 1056 + (ln << 4);
                #pragma unroll
                for (int kw = 0; kw < 3; ++kw) {
                    const int tap = kh * 3 + kw;
                    #pragma unroll
                    for (int q = 0; q < 2; ++q) {
                        const char* pB = rowp + q * 2112 + (kw << 4);
                        const s8v b0 = *(const s8v*)pB;           // px = w0+ln+kw-1
                        const s8v b1 = *(const s8v*)(pB + 512);   // px +32
                        acc0 = __builtin_amdgcn_mfma_f32_32x32x16_bf16(A[tap][q], b0, acc0, 0, 0, 0);
                        acc1 = __builtin_amdgcn_mfma_f32_32x32x16_bf16(A[tap][q], b1, acc1, 0, 0, 0);
                    }
                }
            }

            const int h = h0 + hr;
            float* op = out + ((size_t)n << 21) + (size_t)h * 256 + w0 + ln;
            #pragma unroll
            for (int rg = 0; rg < 16; ++rg) {
                const int o = (rg & 3) + 8 * (rg >> 2) + 4 * g;
                op[(size_t)o * 65536]      = scale * acc0[rg] + bias_r[rg];
                op[(size_t)o * 65536 + 32] = scale * acc1[rg] + bias_r[rg];
            }
        }
    };

    // ---- pipeline: prologue stages tile 0, then issue(t+1) | compute(t) | write(t+1)
    const int hs0 = hsq << 2;
    issueA(hs0);
    writeC(hs0, lds);
    __syncthreads();

    #pragma unroll
    for (int tt = 0; tt < NT; ++tt) {
        char* cur = lds + (tt & 1) * TILEB;
        char* nxt = lds + ((tt + 1) & 1) * TILEB;
        if (tt < NT - 1) issueA(hs0 + tt + 1);
        __builtin_amdgcn_sched_barrier(0);           // pin: loads issued before compute
        compute(hs0 + tt, cur);
        if (tt < NT - 1) {
            writeC(hs0 + tt + 1, nxt);
            __syncthreads();                         // one barrier per tile
        }
    }
}

extern "C" void kernel_launch(void* const* d_in, const int* in_sizes, int n_in,
                              void* d_out, int out_size, void* d_ws, size_t ws_size,
                              hipStream_t stream) {
    const float* x     = (const float*)d_in[0];
    const float* wgt   = (const float*)d_in[1];
    const float* bias  = (const float*)d_in[2];
    const float* scale = (const float*)d_in[3];
    float* out = (float*)d_out;
    k_fused<<<dim3(256), dim3(512), 0, stream>>>(x, wgt, bias, scale, out);
}

// Round 11
// 61.845 us; speedup vs baseline: 1.1595x; 1.1595x over previous
//
#include <hip/hip_runtime.h>

typedef unsigned short u16;
typedef unsigned int   u32;
typedef short s8v  __attribute__((ext_vector_type(8)));   // 8 bf16 (4 VGPR)
typedef float f16v __attribute__((ext_vector_type(16)));  // 32x32 acc
typedef unsigned int u32x4 __attribute__((ext_vector_type(4)));

#define ROWBYTES 4224                 // 4 c-chunks * (66 px * 16 B)
#define NROWS    18                   // 16 output rows + 2 halo
#define TILEB    (NROWS * ROWBYTES)   // 76032 B per buffer
#define NT       4                    // tiles per persistent block

__device__ inline u16 f2bf(float f) {
    u32 u = __builtin_bit_cast(u32, f);
    u += 0x7FFFu + ((u >> 16) & 1u);   // RNE; inputs finite
    return (u16)(u >> 16);
}
__device__ inline u32 pk2(float lo, float hi) {
    return (u32)f2bf(lo) | ((u32)f2bf(hi) << 16);
}

// Producer/consumer fused conv: 256 persistent blocks (1/CU), 512 thr = 8 waves.
// Waves 0-3 stage tile t+1 (f32 load -> bf16 pack -> LDS) while waves 4-7 run
// MFMA + stores on tile t from the other 76KB buffer. One barrier per tile.
// Load and store streams are concurrent by construction -> no phase lock.
__global__ __launch_bounds__(512, 1) void k_fused(const float* __restrict__ x,
                                                  const float* __restrict__ wgt,
                                                  const float* __restrict__ bias,
                                                  const float* __restrict__ scale_p,
                                                  float* __restrict__ out) {
    __shared__ __align__(16) char lds[2 * TILEB];   // 152064 B

    // XCD swizzle (grid 256): 32 dispatch-consecutive blocks = 2 full images
    const int bid     = blockIdx.x;
    const int logical = ((bid & 7) << 5) | (bid >> 3);
    const int n   = logical >> 4;
    const int hq  = (logical >> 2) & 3;              // vertical quarter (64 rows)
    const int wb  = logical & 3;
    const int w0  = wb << 6;
    const int t    = threadIdx.x;
    const int l    = t & 63;
    const int wave = t >> 6;                         // 0..7
    const int g    = l >> 5;
    const int ln   = l & 31;

    // ---- weight repack into buf0 overlay: [o][c][9] f32 -> [tap][o*32+c] bf16
    {
        u16* wl = (u16*)lds;
        #pragma unroll
        for (int k = 0; k < 18; ++k) {               // 9216 = 18*512
            const int idx = t + (k << 9);
            const int tap = idx % 9;
            const int oc  = idx / 9;
            wl[tap * 1024 + oc] = f2bf(wgt[idx]);
        }
    }
    __syncthreads();

    // consumers load A-frags + bias (keeps producer register pressure low)
    s8v A[9][2];
    float bias_r[16];
    if (wave >= 4) {
        const u16* wl = (const u16*)lds;
        #pragma unroll
        for (int tap = 0; tap < 9; ++tap)
            #pragma unroll
            for (int q = 0; q < 2; ++q)
                A[tap][q] = *(const s8v*)(wl + tap * 1024 + ln * 32 + q * 16 + g * 8);
        #pragma unroll
        for (int rg = 0; rg < 16; ++rg) bias_r[rg] = bias[(rg & 3) + 8 * (rg >> 2) + 4 * g];
    }
    const float scale = scale_p[0];
    __syncthreads();   // weights consumed; buf0 free for tile data

    const float* xbase = x + ((size_t)n << 21);      // n*32*65536
    const int hbase = hq << 6;

    // ---- halo helper pieces (threads t<144): (cc, side, r) from t
    const int h_cc   = t / 36;
    const int h_rem  = t - h_cc * 36;
    const int h_side = h_rem / 18;
    const int h_r    = h_rem - h_side * 18;
    const int h_wg   = w0 - 1 + h_side * 65;
    const int h_wcl  = h_wg < 0 ? 0 : (h_wg > 255 ? 255 : h_wg);

    // ---- prologue: all 8 waves stage tile 0 into buf0
    {
        const int h0 = hbase;
        const int chunk = wave & 3, half = wave >> 2;
        const float* pb = xbase + (size_t)(chunk * 8) * 65536 + w0 + l;
        char* ldst = lds + chunk * 1056 + ((l + 1) << 4);
        #pragma unroll
        for (int j = 0; j < 9; ++j) {
            const int r   = half + (j << 1);
            const int hin = h0 - 1 + r;
            const int hcl = hin < 0 ? 0 : (hin > 255 ? 255 : hin);
            const float* p = pb + (size_t)hcl * 256;
            float v[8];
            #pragma unroll
            for (int c = 0; c < 8; ++c) v[c] = p[(size_t)c * 65536];
            const bool bad = (hin < 0) || (hin > 255);
            #pragma unroll
            for (int c = 0; c < 8; ++c) v[c] = bad ? 0.f : v[c];
            *(u32x4*)(ldst + r * ROWBYTES) = u32x4{pk2(v[0], v[1]), pk2(v[2], v[3]),
                                                   pk2(v[4], v[5]), pk2(v[6], v[7])};
        }
        if (t < 144) {
            const int hin = h0 - 1 + h_r;
            const int hcl = hin < 0 ? 0 : (hin > 255 ? 255 : hin);
            const float* p = xbase + (size_t)(h_cc * 8) * 65536 + (size_t)hcl * 256 + h_wcl;
            float hv[8];
            #pragma unroll
            for (int c = 0; c < 8; ++c) hv[c] = p[(size_t)c * 65536];
            const bool bad = (hin < 0) || (hin > 255) || (h_wg < 0) || (h_wg > 255);
            #pragma unroll
            for (int c = 0; c < 8; ++c) hv[c] = bad ? 0.f : hv[c];
            *(u32x4*)(lds + h_r * ROWBYTES + h_cc * 1056 + h_side * 1040) =
                u32x4{pk2(hv[0], hv[1]), pk2(hv[2], hv[3]), pk2(hv[4], hv[5]), pk2(hv[6], hv[7])};
        }
    }
    __syncthreads();

    // ---- producer staging of one tile (waves 0-3): depth-2 two-row pipeline
    float vA[2][8], vB[2][8];
    auto loadU = [&](int u, float (&V)[2][8], const float* pb, int h0) {
        #pragma unroll
        for (int rr = 0; rr < 2; ++rr) {
            const int hin = h0 - 1 + 2 * u + rr;
            const int hcl = hin < 0 ? 0 : (hin > 255 ? 255 : hin);
            const float* p = pb + (size_t)hcl * 256;
            #pragma unroll
            for (int c = 0; c < 8; ++c) V[rr][c] = p[(size_t)c * 65536];
        }
    };
    auto packU = [&](int u, float (&V)[2][8], char* ldst, int h0) {
        #pragma unroll
        for (int rr = 0; rr < 2; ++rr) {
            const int r   = 2 * u + rr;
            const int hin = h0 - 1 + r;
            const bool bad = (hin < 0) || (hin > 255);
            #pragma unroll
            for (int c = 0; c < 8; ++c) V[rr][c] = bad ? 0.f : V[rr][c];
            *(u32x4*)(ldst + r * ROWBYTES) = u32x4{pk2(V[rr][0], V[rr][1]), pk2(V[rr][2], V[rr][3]),
                                                   pk2(V[rr][4], V[rr][5]), pk2(V[rr][6], V[rr][7])};
        }
    };

    for (int tt = 0; tt < NT; ++tt) {
        char* cur = lds + (tt & 1) * TILEB;
        char* nxt = lds + ((tt + 1) & 1) * TILEB;

        if (wave < 4) {
            // -------- producer: stage tile tt+1 into nxt
            if (tt < NT - 1) {
                const int h0 = hbase + ((tt + 1) << 4);
                const int chunk = wave;
                const float* pb = xbase + (size_t)(chunk * 8) * 65536 + w0 + l;
                char* ldst = nxt + chunk * 1056 + ((l + 1) << 4);
                // halo loads issued first (latency-hidden by main pipeline)
                float hv[8];
                int h_hin = 0;
                if (t < 144) {
                    h_hin = h0 - 1 + h_r;
                    const int hcl = h_hin < 0 ? 0 : (h_hin > 255 ? 255 : h_hin);
                    const float* p = xbase + (size_t)(h_cc * 8) * 65536 + (size_t)hcl * 256 + h_wcl;
                    #pragma unroll
                    for (int c = 0; c < 8; ++c) hv[c] = p[(size_t)c * 65536];
                }
                loadU(0, vA, pb, h0);
                #pragma unroll
                for (int i = 0; i < 4; ++i) {
                    loadU(2 * i + 1, vB, pb, h0);
                    packU(2 * i,     vA, ldst, h0);
                    loadU(2 * i + 2, vA, pb, h0);
                    packU(2 * i + 1, vB, ldst, h0);
                }
                packU(8, vA, ldst, h0);
                if (t < 144) {
                    const bool bad = (h_hin < 0) || (h_hin > 255) || (h_wg < 0) || (h_wg > 255);
                    #pragma unroll
                    for (int c = 0; c < 8; ++c) hv[c] = bad ? 0.f : hv[c];
                    *(u32x4*)(nxt + h_r * ROWBYTES + h_cc * 1056 + h_side * 1040) =
                        u32x4{pk2(hv[0], hv[1]), pk2(hv[2], hv[3]), pk2(hv[4], hv[5]), pk2(hv[6], hv[7])};
                }
            }
        } else {
            // -------- consumer: compute tile tt from cur (4 rows per wave)
            const int h0 = hbase + (tt << 4);
            const int cw = wave - 4;
            #pragma unroll
            for (int i = 0; i < 4; ++i) {
                const int hr = (cw << 2) + i;        // 0..15

                f16v acc0, acc1;
                #pragma unroll
                for (int rg = 0; rg < 16; ++rg) { acc0[rg] = 0.f; acc1[rg] = 0.f; }

                #pragma unroll
                for (int kh = 0; kh < 3; ++kh) {
                    const char* rowp = cur + (hr + kh) * ROWBYTES + g * 1056 + (ln << 4);
                    #pragma unroll
                    for (int kw = 0; kw < 3; ++kw) {
                        const int tap = kh * 3 + kw;
                        #pragma unroll
                        for (int q = 0; q < 2; ++q) {
                            const char* pB = rowp + q * 2112 + (kw << 4);
                            const s8v b0 = *(const s8v*)pB;           // px = w0+ln+kw-1
                            const s8v b1 = *(const s8v*)(pB + 512);   // px +32
                            acc0 = __builtin_amdgcn_mfma_f32_32x32x16_bf16(A[tap][q], b0, acc0, 0, 0, 0);
                            acc1 = __builtin_amdgcn_mfma_f32_32x32x16_bf16(A[tap][q], b1, acc1, 0, 0, 0);
                        }
                    }
                }

                const int h = h0 + hr;
                float* op = out + ((size_t)n << 21) + (size_t)h * 256 + w0 + ln;
                #pragma unroll
                for (int rg = 0; rg < 16; ++rg) {
                    const int o = (rg & 3) + 8 * (rg >> 2) + 4 * g;
                    op[(size_t)o * 65536]      = scale * acc0[rg] + bias_r[rg];
                    op[(size_t)o * 65536 + 32] = scale * acc1[rg] + bias_r[rg];
                }
            }
        }
        __syncthreads();   // one barrier per tile
    }
}

extern "C" void kernel_launch(void* const* d_in, const int* in_sizes, int n_in,
                              void* d_out, int out_size, void* d_ws, size_t ws_size,
                              hipStream_t stream) {
    const float* x     = (const float*)d_in[0];
    const float* wgt   = (const float*)d_in[1];
    const float* bias  = (const float*)d_in[2];
    const float* scale = (const float*)d_in[3];
    float* out = (float*)d_out;
    k_fused<<<dim3(256), dim3(512), 0, stream>>>(x, wgt, bias, scale, out);
}

// Round 12
// 56.809 us; speedup vs baseline: 1.2623x; 1.0886x over previous
//
#include <hip/hip_runtime.h>

typedef unsigned short u16;
typedef unsigned int   u32;
typedef short s8v  __attribute__((ext_vector_type(8)));   // 8 bf16 (4 VGPR)
typedef float f16v __attribute__((ext_vector_type(16)));  // 32x32 acc
typedef unsigned int u32x4 __attribute__((ext_vector_type(4)));

#define ROWBYTES 4224                 // 4 c-chunks * (66 px * 16 B)
#define NROWS    18                   // 16 output rows + 2 halo
#define LDS_BYTES (NROWS * ROWBYTES)  // 76032 -> 2 blocks/CU

__device__ inline u16 f2bf(float f) {
    u32 u = __builtin_bit_cast(u32, f);
    u += 0x7FFFu + ((u >> 16) & 1u);   // RNE; inputs finite
    return (u16)(u >> 16);
}
__device__ inline u32 pk2(float lo, float hi) {
    return (u32)f2bf(lo) | ((u32)f2bf(hi) << 16);
}

// Fused conv, R6 structure + h-major (DRAM-page-sequential) staging loads:
// each wave walks 18 rows of ONE channel back-to-back (256B segs, 1KB stride
// = same-page bursts) instead of hopping 256KB between channels per load.
// Same LDS layout/bytes as R6; only load ORDER changes.
// Block: 256 thr = 4 waves; owns 32o x 64w x 16h. Grid: 16n*16hs*4wb = 1024.
__global__ __launch_bounds__(256, 2) void k_fused(const float* __restrict__ x,
                                                  const float* __restrict__ wgt,
                                                  const float* __restrict__ bias,
                                                  const float* __restrict__ scale_p,
                                                  float* __restrict__ out) {
    __shared__ __align__(16) char lds[LDS_BYTES];

    // bijective XCD swizzle: 8 consecutive logical blocks -> same XCD
    const int b    = ((blockIdx.x & 7) << 7) | (blockIdx.x >> 3);   // grid 1024
    const int wb   = b & 3;
    const int hs   = (b >> 2) & 15;
    const int n    = b >> 6;
    const int w0   = wb << 6;
    const int h0   = hs << 4;
    const int t    = threadIdx.x;
    const int l    = t & 63;
    const int wave = t >> 6;
    const int g    = l >> 5;
    const int ln   = l & 31;

    // ---- weight repack into LDS overlay: [o][c][9] f32 -> [tap][o*32+c] bf16
    {
        u16* wl = (u16*)lds;
        #pragma unroll
        for (int k = 0; k < 36; ++k) {
            const int idx = t + (k << 8);
            const int tap = idx % 9;
            const int oc  = idx / 9;
            wl[tap * 1024 + oc] = f2bf(wgt[idx]);
        }
    }
    __syncthreads();

    // A frags: wt[tap][o=ln][c = q*16 + g*8 + e]
    s8v A[9][2];
    {
        const u16* wl = (const u16*)lds;
        #pragma unroll
        for (int tap = 0; tap < 9; ++tap)
            #pragma unroll
            for (int q = 0; q < 2; ++q)
                A[tap][q] = *(const s8v*)(wl + tap * 1024 + ln * 32 + q * 16 + g * 8);
    }
    const float scale = scale_p[0];
    float bias_r[16];
    #pragma unroll
    for (int rg = 0; rg < 16; ++rg) bias_r[rg] = bias[(rg & 3) + 8 * (rg >> 2) + 4 * g];
    __syncthreads();   // weight overlay free

    const float* xbase = x + ((size_t)n << 21);           // n*32*65536

    // ---- halo px (ps=0, ps=65): 144 gather threads, u32x4 writes
    if (t < 144) {
        const int cc   = t / 36;
        const int rem  = t - cc * 36;
        const int side = rem / 18;
        const int r    = rem - side * 18;
        const int hin  = h0 - 1 + r;
        const int wg   = w0 - 1 + side * 65;
        u32 q0 = 0, q1 = 0, q2 = 0, q3 = 0;
        if (hin >= 0 && hin < 256 && wg >= 0 && wg < 256) {
            const float* p = xbase + (size_t)(cc * 8) * 65536 + (size_t)hin * 256 + wg;
            q0 = pk2(p[0],      p[65536]);
            q1 = pk2(p[131072], p[196608]);
            q2 = pk2(p[262144], p[327680]);
            q3 = pk2(p[393216], p[458752]);
        }
        *(u32x4*)(lds + r * ROWBYTES + cc * 1056 + side * 1040) = u32x4{q0, q1, q2, q3};
    }

    // ---- main staging, h-major per channel-pair: wave = c-chunk (8 channels),
    // lane l -> px w0+l (ps=l+1). For each pair j: 18 page-sequential loads of
    // channel 2j, then 18 of channel 2j+1, then pack+write 18 u32s.
    {
        const float* pc = xbase + (size_t)(wave * 8) * 65536 + w0 + l;
        char* ldst = lds + wave * 1056 + ((l + 1) << 4);
        #pragma unroll
        for (int j = 0; j < 4; ++j) {
            const float* p0 = pc + (size_t)(2 * j) * 65536;
            const float* p1 = p0 + 65536;
            float a[NROWS], c2[NROWS];
            #pragma unroll
            for (int r = 0; r < NROWS; ++r) {             // channel 2j: 18 seq rows
                const int hin = h0 - 1 + r;
                const int hcl = hin < 0 ? 0 : (hin > 255 ? 255 : hin);
                a[r] = p0[(size_t)hcl * 256];
            }
            #pragma unroll
            for (int r = 0; r < NROWS; ++r) {             // channel 2j+1: 18 seq rows
                const int hin = h0 - 1 + r;
                const int hcl = hin < 0 ? 0 : (hin > 255 ? 255 : hin);
                c2[r] = p1[(size_t)hcl * 256];
            }
            #pragma unroll
            for (int r = 0; r < NROWS; ++r) {
                const int hin = h0 - 1 + r;
                const bool bad = (hin < 0) || (hin > 255);
                const u32 pk = bad ? 0u : pk2(a[r], c2[r]);
                *(u32*)(ldst + r * ROWBYTES + (j << 2)) = pk;
            }
        }
    }
    __syncthreads();   // the only barrier before compute

    // ---- compute: each wave does 4 output rows, barrier-free
    #pragma unroll
    for (int i = 0; i < 4; ++i) {
        const int hr = (wave << 2) + i;                   // 0..15

        f16v acc0, acc1;
        #pragma unroll
        for (int rg = 0; rg < 16; ++rg) { acc0[rg] = 0.f; acc1[rg] = 0.f; }

        #pragma unroll
        for (int kh = 0; kh < 3; ++kh) {
            const char* rowp = lds + (hr + kh) * ROWBYTES + g * 1056 + (ln << 4);
            #pragma unroll
            for (int kw = 0; kw < 3; ++kw) {
                const int tap = kh * 3 + kw;
                #pragma unroll
                for (int q = 0; q < 2; ++q) {
                    const char* pB = rowp + q * 2112 + (kw << 4);
                    const s8v b0 = *(const s8v*)pB;           // px = w0+ln+kw-1
                    const s8v b1 = *(const s8v*)(pB + 512);   // px +32
                    acc0 = __builtin_amdgcn_mfma_f32_32x32x16_bf16(A[tap][q], b0, acc0, 0, 0, 0);
                    acc1 = __builtin_amdgcn_mfma_f32_32x32x16_bf16(A[tap][q], b1, acc1, 0, 0, 0);
                }
            }
        }

        // epilogue: D col(px)=ln, row(o)=(rg&3)+8*(rg>>2)+4*g
        const int h = h0 + hr;
        float* op = out + ((size_t)n << 21) + (size_t)h * 256 + w0 + ln;
        #pragma unroll
        for (int rg = 0; rg < 16; ++rg) {
            const int o = (rg & 3) + 8 * (rg >> 2) + 4 * g;
            op[(size_t)o * 65536]      = scale * acc0[rg] + bias_r[rg];
            op[(size_t)o * 65536 + 32] = scale * acc1[rg] + bias_r[rg];
        }
    }
}

extern "C" void kernel_launch(void* const* d_in, const int* in_sizes, int n_in,
                              void* d_out, int out_size, void* d_ws, size_t ws_size,
                              hipStream_t stream) {
    const float* x     = (const float*)d_in[0];
    const float* wgt   = (const float*)d_in[1];
    const float* bias  = (const float*)d_in[2];
    const float* scale = (const float*)d_in[3];
    float* out = (float*)d_out;
    k_fused<<<dim3(1024), dim3(256), 0, stream>>>(x, wgt, bias, scale, out);
}